// Round 2
// baseline (8366.720 us; speedup 1.0000x reference)
//
#include <hip/hip_runtime.h>

#define Bdim 64
#define Tdim 512
#define Fdim 512
#define Hdim 1024
#define NKB  48          // K-blocks of 32: 16 for x (K=512) + 32 for h (K=1024)
#define NXKB 16
#define NHKB 32
#define NWG  128
#define NTHR 256

typedef __attribute__((ext_vector_type(8))) _Float16            f16x8;
typedef __attribute__((ext_vector_type(4))) float               f32x4;
typedef __attribute__((ext_vector_type(2))) unsigned long long  u64x2;

#define MFMA(a, b, c) __builtin_amdgcn_mfma_f32_16x16x32_f16((a), (b), (c), 0, 0, 0)

// ---- workspace layout (bytes) ----
#define WP_ELEMS  (256*48*64*8)                      // fp16 fragment-linear weights
#define BIAS_OFF  ((size_t)WP_ELEMS * 2)
#define HBUF_OFF  (BIAS_OFF + 4096 * 4)              // fp16[2][64][1024] double buffer
#define CNT_OFF   (HBUF_OFF + (size_t)2 * Bdim * Hdim * 2)  // barrier counter (uint)

__device__ __forceinline__ float sigmoidf_(float v) {
    return 1.0f / (1.0f + __expf(-v));
}
__device__ __forceinline__ float tanhf_(float v) {
    return 1.0f - 2.0f / (1.0f + __expf(2.0f * v));
}

// Packed col Np = wg*32 + gate*8 + c  <->  orig col n = gate*1024 + wg*8 + c.
// Wp8[(tile*48 + kb)*64 + lane] = Wfull[kb*32 + (lane>>4)*8 + j][orig(tile*16 + (lane&15))]
__global__ void pack_w_kernel(const float* __restrict__ Wi, const float* __restrict__ Wh,
                              _Float16* __restrict__ Wp)
{
    int d = blockIdx.x * blockDim.x + threadIdx.x;   // 0 .. 786431
    int tn   = d / 3072;
    int r    = d % 3072;
    int kb   = r / 64;
    int lane = r % 64;
    int kg = lane >> 4, lm = lane & 15;
    int Np = tn * 16 + lm;
    int g    = Np >> 5;
    int lc   = Np & 31;
    int gate = lc >> 3, c = lc & 7;
    int n  = gate * Hdim + g * 8 + c;
    int k0 = kb * 32 + kg * 8;
    f16x8 v;
#pragma unroll
    for (int j = 0; j < 8; ++j) {
        int k = k0 + j;
        float w = (k < Fdim) ? Wi[(long)k * 4096 + n] : Wh[(long)(k - Fdim) * 4096 + n];
        v[j] = (_Float16)w;
    }
    ((f16x8*)Wp)[d] = v;
}

__global__ void pack_misc_kernel(const float* __restrict__ bh, const float* __restrict__ h0,
                                 float* __restrict__ bias_p, _Float16* __restrict__ hbuf,
                                 unsigned int* __restrict__ cnt)
{
    int t = blockIdx.x * blockDim.x + threadIdx.x;
    if (t == 0) cnt[0] = 0u;                          // re-armed every launch
    if (t < 4096) {
        int g = t >> 5, lc = t & 31;
        int gate = lc >> 3, c = lc & 7;
        bias_p[t] = bh[gate * Hdim + g * 8 + c];
    }
    if (t < Bdim * Hdim) {
        hbuf[t] = (_Float16)h0[t];                    // buffer 0 = h at t=0
    }
}

__global__ __launch_bounds__(NTHR, 1)
void lstm_kernel(const float* __restrict__ x, const float* __restrict__ c0,
                 const f16x8* __restrict__ Wp8, const float* __restrict__ bias_p,
                 unsigned int* __restrict__ hbuf, unsigned int* __restrict__ cnt,
                 float* __restrict__ out)
{
    __shared__ f16x8 wlds[2 * NKB * 64];              // 96 KiB weight slice
    __shared__ float zlds[Bdim][33];                  // 8.25 KiB

    const int wg   = blockIdx.x;
    const int tid  = threadIdx.x;
    const int wave = tid >> 6;
    const int lane = tid & 63;
    const int kg = lane >> 4;
    const int lm = lane & 15;

    // ---- stage the WG's weight slice into LDS once ----
    {
        const f16x8* src = Wp8 + (size_t)wg * 2 * NKB * 64;
        for (int e = tid; e < 2 * NKB * 64; e += NTHR) wlds[e] = src[e];
    }

    const float bias0 = bias_p[wg * 32 + lm];
    const float bias1 = bias_p[wg * 32 + 16 + lm];

    // gate-phase ownership: thread owns h cols (jl0, jl0+1) of batch row b0
    const int p0 = tid * 2;
    const int b0 = p0 >> 3, jl0 = p0 & 7;             // jl0 even
    const int jc = wg * 8;
    float cc0 = c0[b0 * Hdim + jc + jl0];
    float cc1 = c0[b0 * Hdim + jc + jl0 + 1];

    const int arow = wave * 16 + lm;                  // MFMA A-operand row (batch)
    const float* __restrict__ xrow = x + (size_t)arow * Tdim * Fdim + kg * 8;

    // ---- prefetch x fragments for t=0 ----
    f16x8 xf[NXKB];
#pragma unroll
    for (int kb = 0; kb < NXKB; ++kb) {
        const float* ap = xrow + kb * 32;
        f16x8 a;
#pragma unroll
        for (int j = 0; j < 8; ++j) a[j] = (_Float16)ap[j];
        xf[kb] = a;
    }

    // h A-fragment addressing in u64 units (8 halves = 16B = 2 u64 per fragment)
    const unsigned long long* __restrict__ hbase64 =
        (const unsigned long long*)hbuf + (size_t)arow * (Hdim / 4) + kg * 2;

    __syncthreads();                                  // wlds ready

    for (int t = 0; t < Tdim; ++t) {
        const int cur = t & 1;
        const unsigned long long* hb64 = hbase64 + (size_t)cur * (Bdim * Hdim / 4);

        f32x4 acc0a = {bias0, bias0, bias0, bias0};
        f32x4 acc1a = {bias1, bias1, bias1, bias1};
        f32x4 acc0b = {0.f, 0.f, 0.f, 0.f};
        f32x4 acc1b = {0.f, 0.f, 0.f, 0.f};

        // ---- x part of K (from registers) ----
#pragma unroll 4
        for (int kb = 0; kb < NXKB; ++kb) {
            f16x8 a   = xf[kb];
            f16x8 bf0 = wlds[kb * 64 + lane];
            f16x8 bf1 = wlds[NKB * 64 + kb * 64 + lane];
            if (kb & 1) { acc0b = MFMA(a, bf0, acc0b); acc1b = MFMA(a, bf1, acc1b); }
            else        { acc0a = MFMA(a, bf0, acc0a); acc1a = MFMA(a, bf1, acc1a); }
        }
        // ---- h part of K: agent-scope (L2-bypassing) loads from hbuf ----
#pragma unroll 4
        for (int kb = 0; kb < NHKB; ++kb) {
            const unsigned long long* hp = hb64 + kb * 8;
            u64x2 r;
            r.x = __hip_atomic_load(hp,     __ATOMIC_RELAXED, __HIP_MEMORY_SCOPE_AGENT);
            r.y = __hip_atomic_load(hp + 1, __ATOMIC_RELAXED, __HIP_MEMORY_SCOPE_AGENT);
            f16x8 a   = __builtin_bit_cast(f16x8, r);
            f16x8 bf0 = wlds[(NXKB + kb) * 64 + lane];
            f16x8 bf1 = wlds[NKB * 64 + (NXKB + kb) * 64 + lane];
            if (kb & 1) { acc0b = MFMA(a, bf0, acc0b); acc1b = MFMA(a, bf1, acc1b); }
            else        { acc0a = MFMA(a, bf0, acc0a); acc1a = MFMA(a, bf1, acc1a); }
        }
        f32x4 z0 = acc0a + acc0b;
        f32x4 z1 = acc1a + acc1b;

        // D layout: row = (lane>>4)*4 + r, col = lane&15
        {
            int rbase = wave * 16 + kg * 4;
#pragma unroll
            for (int r = 0; r < 4; ++r) {
                zlds[rbase + r][lm]      = z0[r];
                zlds[rbase + r][16 + lm] = z1[r];
            }
        }
        __syncthreads();

        // ---- gates (local cols: i 0..7, f 8..15, g 16..23, o 24..31) ----
        float zi0 = zlds[b0][jl0],      zi1 = zlds[b0][jl0 + 1];
        float zf0 = zlds[b0][8 + jl0],  zf1 = zlds[b0][8 + jl0 + 1];
        float zg0 = zlds[b0][16 + jl0], zg1 = zlds[b0][16 + jl0 + 1];
        float zo0 = zlds[b0][24 + jl0], zo1 = zlds[b0][24 + jl0 + 1];

        float i0 = sigmoidf_(zi0), f0 = sigmoidf_(zf0);
        float g0 = tanhf_(zg0),    o0 = sigmoidf_(zo0);
        cc0 = f0 * cc0 + i0 * g0;
        float hv0 = o0 * tanhf_(cc0);

        float i1 = sigmoidf_(zi1), f1 = sigmoidf_(zf1);
        float g1 = tanhf_(zg1),    o1 = sigmoidf_(zo1);
        cc1 = f1 * cc1 + i1 * g1;
        float hv1 = o1 * tanhf_(cc1);

        // publish h(t+1): packed 2x fp16 agent-scope store (write-through to MALL)
        {
            union { _Float16 h[2]; unsigned int u; } pk;
            pk.h[0] = (_Float16)hv0; pk.h[1] = (_Float16)hv1;
            unsigned int hidx = (unsigned int)((b0 * Hdim + jc + jl0) >> 1);
            __hip_atomic_store(hbuf + (size_t)(cur ^ 1) * (Bdim * Hdim / 2) + hidx,
                               pk.u, __ATOMIC_RELAXED, __HIP_MEMORY_SCOPE_AGENT);
        }
        __syncthreads();                              // drains all waves' h stores (vmcnt 0)

        // ---- barrier arrive early, then useful work, then wait ----
        if (tid == 0)
            __hip_atomic_fetch_add(cnt, 1u, __ATOMIC_RELEASE, __HIP_MEMORY_SCOPE_AGENT);

        {   // out store (no cross-WG dependency)
            float2 ov; ov.x = hv0; ov.y = hv1;
            *(float2*)(out + ((size_t)b0 * Tdim + t) * Hdim + jc + jl0) = ov;
        }
        {   // prefetch x fragments for t+1 (plain cached loads; x is read-only)
            int tn = (t + 1 < Tdim) ? (t + 1) : t;
            const float* xp = xrow + (size_t)tn * Fdim;
#pragma unroll
            for (int kb = 0; kb < NXKB; ++kb) {
                const float* ap = xp + kb * 32;
                f16x8 a;
#pragma unroll
                for (int j = 0; j < 8; ++j) a[j] = (_Float16)ap[j];
                xf[kb] = a;
            }
        }

        if (tid == 0) {
            const unsigned int target = (unsigned int)(t + 1) * NWG;
            while (__hip_atomic_load(cnt, __ATOMIC_RELAXED, __HIP_MEMORY_SCOPE_AGENT) < target)
                __builtin_amdgcn_s_sleep(2);
        }
        __syncthreads();
    }
}

extern "C" void kernel_launch(void* const* d_in, const int* in_sizes, int n_in,
                              void* d_out, int out_size, void* d_ws, size_t ws_size,
                              hipStream_t stream)
{
    const float* x  = (const float*)d_in[0];
    const float* c0 = (const float*)d_in[1];
    const float* h0 = (const float*)d_in[2];
    const float* Wi = (const float*)d_in[3];
    const float* Wh = (const float*)d_in[4];
    const float* bh = (const float*)d_in[5];
    float* out = (float*)d_out;

    char* ws = (char*)d_ws;
    _Float16*     Wp     = (_Float16*)(ws);
    float*        bias_p = (float*)(ws + BIAS_OFF);
    _Float16*     hbufh  = (_Float16*)(ws + HBUF_OFF);
    unsigned int* hbuf   = (unsigned int*)(ws + HBUF_OFF);
    unsigned int* cnt    = (unsigned int*)(ws + CNT_OFF);

    hipLaunchKernelGGL(pack_w_kernel,    dim3(3072), dim3(256), 0, stream, Wi, Wh, Wp);
    hipLaunchKernelGGL(pack_misc_kernel, dim3(256),  dim3(256), 0, stream, bh, h0, bias_p, hbufh, cnt);
    hipLaunchKernelGGL(lstm_kernel, dim3(NWG), dim3(NTHR), 0, stream,
                       x, c0, (const f16x8*)Wp, bias_p, hbuf, cnt, out);
}